// Round 2
// baseline (394.996 us; speedup 1.0000x reference)
//
#include <hip/hip_runtime.h>

typedef _Float16 f16;
typedef _Float16 f16x8 __attribute__((ext_vector_type(8)));
typedef _Float16 f16x4 __attribute__((ext_vector_type(4)));
typedef float f32x4 __attribute__((ext_vector_type(4)));

#define MFMA16(a, b, c) __builtin_amdgcn_mfma_f32_16x16x32_f16((a), (b), (c), 0, 0, 0)

// ---------------------------------------------------------------------------
// fp32 -> fp16 conversion (x)
__global__ void cvt_x(const float* __restrict__ in, f16* __restrict__ out, int n) {
    int i4 = (blockIdx.x * 256 + threadIdx.x) * 4;
    if (i4 >= n) return;
    float4 v = *reinterpret_cast<const float4*>(in + i4);
    f16x4 o;
    o[0] = (f16)v.x; o[1] = (f16)v.y; o[2] = (f16)v.z; o[3] = (f16)v.w;
    *reinterpret_cast<f16x4*>(out + i4) = o;
}

// ---------------------------------------------------------------------------
// transpose fp32 [K][N] -> fp16 [N][K]   (K,N multiples of 64)
__global__ void wtrans(const float* __restrict__ in, f16* __restrict__ out, int K, int N) {
    __shared__ f16 tile[64][65];
    int n0 = blockIdx.x * 64, k0 = blockIdx.y * 64;
    int c = threadIdx.x & 63, rb = threadIdx.x >> 6;
#pragma unroll
    for (int it = 0; it < 16; ++it) {
        int r = rb + it * 4;
        tile[r][c] = (f16)in[(size_t)(k0 + r) * N + n0 + c];
    }
    __syncthreads();
#pragma unroll
    for (int it = 0; it < 16; ++it) {
        int rr = rb + it * 4;
        out[(size_t)(n0 + rr) * K + k0 + c] = tile[c][rr];
    }
}

// ---------------------------------------------------------------------------
// GEMM: C[M][N] = A[M][K] @ Bt[N][K]^T + bias, fp16 in, fp32 accum.
// Block 256 threads = 4 waves; each wave does a 16x64 tile; block covers 64x64.
__global__ __launch_bounds__(256) void gemm_f16(
    const f16* __restrict__ A, const f16* __restrict__ Bt,
    const float* __restrict__ bias, f16* __restrict__ Ch, float* __restrict__ Cf,
    int M, int N, int K) {
    int lane = threadIdx.x & 63, w = threadIdx.x >> 6;
    int lr = lane & 15, lg = lane >> 4;
    int m0 = blockIdx.y * 64 + w * 16;
    int n0 = blockIdx.x * 64;
    int arow = m0 + lr;
    if (arow >= M) arow = M - 1;  // clamp (tail rows write-guarded below)
    const f16* ap = A + (size_t)arow * K + 8 * lg;
    const f16* bp = Bt + (size_t)(n0 + lr) * K + 8 * lg;
    f32x4 acc0 = {0,0,0,0}, acc1 = {0,0,0,0}, acc2 = {0,0,0,0}, acc3 = {0,0,0,0};
    for (int kk = 0; kk < K; kk += 32) {
        f16x8 a  = *reinterpret_cast<const f16x8*>(ap + kk);
        f16x8 b0 = *reinterpret_cast<const f16x8*>(bp + kk);
        f16x8 b1 = *reinterpret_cast<const f16x8*>(bp + (size_t)16 * K + kk);
        f16x8 b2 = *reinterpret_cast<const f16x8*>(bp + (size_t)32 * K + kk);
        f16x8 b3 = *reinterpret_cast<const f16x8*>(bp + (size_t)48 * K + kk);
        acc0 = MFMA16(a, b0, acc0);
        acc1 = MFMA16(a, b1, acc1);
        acc2 = MFMA16(a, b2, acc2);
        acc3 = MFMA16(a, b3, acc3);
    }
    f32x4 accs[4] = {acc0, acc1, acc2, acc3};
    int orow = m0 + 4 * lg;
#pragma unroll
    for (int j = 0; j < 4; ++j) {
        int col = n0 + 16 * j + lr;
        float bv = bias ? bias[col] : 0.f;
#pragma unroll
        for (int r = 0; r < 4; ++r) {
            int rr = orow + r;
            if (rr >= M) continue;
            float v = accs[j][r] + bv;
            if (Ch) Ch[(size_t)rr * N + col] = (f16)v;
            else    Cf[(size_t)rr * N + col] = v;
        }
    }
}

// ---------------------------------------------------------------------------
// RoPE on q,k halves of qkv.  qkv layout [T][3*H*DH] fp16 (bias already added).
__global__ void rope_qk(const f16* __restrict__ qkv, const int* __restrict__ cu,
                        int Bn, int T, f16* __restrict__ qh, f16* __restrict__ kh) {
    int idx = blockIdx.x * 256 + threadIdx.x;
    if (idx >= T * 512) return;
    int i = idx & 31;            // rotary pair index 0..31
    int hh = (idx >> 5) & 15;    // head
    int t = idx >> 9;            // token
    int pos = t;
    for (int q = 0; q < Bn; ++q) {
        int lo = cu[q], hi = cu[q + 1];
        if (t >= lo && t < hi) { pos = t - lo; break; }
    }
    float inv = powf(10000.f, -(float)(2 * i) * (1.f / 64.f));
    float ang = (float)pos * inv;
    float sn, cs;
    sincosf(ang, &sn, &cs);
    size_t base = (size_t)t * 3072 + hh * 64 + i;
    float q1 = (float)qkv[base],        q2 = (float)qkv[base + 32];
    float k1 = (float)qkv[base + 1024], k2 = (float)qkv[base + 1056];
    size_t ob = (size_t)t * 1024 + hh * 64 + i;
    qh[ob]      = (f16)(q1 * cs - q2 * sn);
    qh[ob + 32] = (f16)(q2 * cs + q1 * sn);
    kh[ob]      = (f16)(k1 * cs - k2 * sn);
    kh[ob + 32] = (f16)(k2 * cs + k1 * sn);
}

// ---------------------------------------------------------------------------
// Scatter V into per-(b,h) transposed layout vt[b][h][d][pos], pos-contiguous.
__global__ void v_trans(const f16* __restrict__ qkv, const int* __restrict__ cu,
                        int Bn, int T, int Spad, f16* __restrict__ vt) {
    __shared__ f16 tile[64][65];
    int h = blockIdx.y;
    int t0 = blockIdx.x * 64;
    int c = threadIdx.x & 63, rb = threadIdx.x >> 6;
#pragma unroll
    for (int it = 0; it < 16; ++it) {
        int r = rb + it * 4;
        int t = t0 + r;
        f16 v = (f16)0.f;
        if (t < T) v = qkv[(size_t)t * 3072 + 2048 + h * 64 + c];
        tile[r][c] = v;   // tile[token][dim]
    }
    __syncthreads();
    int t = t0 + c;       // this lane's token
    int bb = 0, pos = -1;
    if (t < T) {
        for (int q = 0; q < Bn; ++q) {
            int lo = cu[q], hi = cu[q + 1];
            if (t >= lo && t < hi) { bb = q; pos = t - lo; }
        }
    }
#pragma unroll
    for (int it = 0; it < 16; ++it) {
        int d = rb + it * 4;  // dim
        // FIX: value is V[token=t0+c][dim=d] = tile[c][d]  (was tile[d][c])
        if (pos >= 0) vt[((size_t)(bb * 16 + h) * 64 + d) * Spad + pos] = tile[c][d];
    }
}

// ---------------------------------------------------------------------------
// Flash attention: one wave per (b, h, 16-q-row block). KV blocks of 32.
__global__ __launch_bounds__(64) void attn_fwd(
    const f16* __restrict__ qh, const f16* __restrict__ kh,
    const f16* __restrict__ vt, const int* __restrict__ cu,
    f16* __restrict__ oh, int Spad) {
    int b = blockIdx.z, h = blockIdx.y;
    int s0 = cu[b];
    int len = cu[b + 1] - s0;
    int q0 = blockIdx.x * 16;
    if (q0 >= len) return;
    int lane = threadIdx.x, lr = lane & 15, lg = lane >> 4;
    __shared__ f16 pl[16 * 32];

    // Q fragments (A-operand): rows q0+lr, k-dim (head dim) split in two 32-chunks
    f16x8 qf0 = {}, qf1 = {};
    int qrow = q0 + lr;
    if (qrow < len) {
        const f16* qp = qh + (size_t)(s0 + qrow) * 1024 + h * 64 + 8 * lg;
        qf0 = *reinterpret_cast<const f16x8*>(qp);
        qf1 = *reinterpret_cast<const f16x8*>(qp + 32);
    }

    float mrun[4], lrun[4];
    f32x4 oacc[4];
#pragma unroll
    for (int r = 0; r < 4; ++r) { mrun[r] = -1e30f; lrun[r] = 0.f; }
#pragma unroll
    for (int dt = 0; dt < 4; ++dt) oacc[dt] = (f32x4){0, 0, 0, 0};

    int kend = min(q0 + 16, len);
    for (int kk0 = 0; kk0 < kend; kk0 += 32) {
        // S tile 16x32 = two 16x16 MFMA tiles
        f32x4 sa[2];
#pragma unroll
        for (int j = 0; j < 2; ++j) {
            int krow = kk0 + 16 * j + lr;
            f16x8 kf0 = {}, kf1 = {};
            if (krow < len) {
                const f16* kp = kh + (size_t)(s0 + krow) * 1024 + h * 64 + 8 * lg;
                kf0 = *reinterpret_cast<const f16x8*>(kp);
                kf1 = *reinterpret_cast<const f16x8*>(kp + 32);
            }
            f32x4 z = {0, 0, 0, 0};
            z = MFMA16(qf0, kf0, z);
            z = MFMA16(qf1, kf1, z);
            sa[j] = z;
        }
        // online softmax (per output row = 4*lg + r)
        float pv[2][4], alpha[4];
#pragma unroll
        for (int r = 0; r < 4; ++r) {
            int qr = q0 + 4 * lg + r;
            float sv[2];
            float mx = -1e30f;
#pragma unroll
            for (int j = 0; j < 2; ++j) {
                int kc = kk0 + 16 * j + lr;
                float v = sa[j][r] * 0.125f;
                if (kc > qr || kc >= len) v = -1e30f;
                sv[j] = v;
                mx = fmaxf(mx, v);
            }
            for (int msk = 1; msk < 16; msk <<= 1) mx = fmaxf(mx, __shfl_xor(mx, msk, 64));
            float mnew = fmaxf(mrun[r], mx);
            float al = __expf(mrun[r] - mnew);
            mrun[r] = mnew;
            float rs = 0.f;
#pragma unroll
            for (int j = 0; j < 2; ++j) {
                float p = __expf(sv[j] - mnew);
                pv[j][r] = p;
                rs += p;
            }
            for (int msk = 1; msk < 16; msk <<= 1) rs += __shfl_xor(rs, msk, 64);
            lrun[r] = lrun[r] * al + rs;
            alpha[r] = al;
        }
#pragma unroll
        for (int dt = 0; dt < 4; ++dt)
#pragma unroll
            for (int r = 0; r < 4; ++r) oacc[dt][r] *= alpha[r];
        // P -> LDS -> A-fragment layout
#pragma unroll
        for (int j = 0; j < 2; ++j)
#pragma unroll
            for (int r = 0; r < 4; ++r)
                pl[(4 * lg + r) * 32 + 16 * j + lr] = (f16)pv[j][r];
        __syncthreads();
        f16x8 pa = *reinterpret_cast<const f16x8*>(pl + lr * 32 + 8 * lg);
        const f16* vb = vt + ((size_t)(b * 16 + h) * 64) * Spad;
#pragma unroll
        for (int dt = 0; dt < 4; ++dt) {
            f16x8 vf = *reinterpret_cast<const f16x8*>(vb + (size_t)(16 * dt + lr) * Spad + kk0 + 8 * lg);
            oacc[dt] = MFMA16(pa, vf, oacc[dt]);
        }
        __syncthreads();
    }
#pragma unroll
    for (int dt = 0; dt < 4; ++dt)
#pragma unroll
        for (int r = 0; r < 4; ++r) {
            int qr = q0 + 4 * lg + r;
            if (qr < len)
                oh[(size_t)(s0 + qr) * 1024 + h * 64 + 16 * dt + lr] = (f16)(oacc[dt][r] / lrun[r]);
        }
}

// ---------------------------------------------------------------------------
extern "C" void kernel_launch(void* const* d_in, const int* in_sizes, int n_in,
                              void* d_out, int out_size, void* d_ws, size_t ws_size,
                              hipStream_t stream) {
    const float* x    = (const float*)d_in[0];
    const float* Wqkv = (const float*)d_in[1];
    const float* bqkv = (const float*)d_in[2];
    const float* Wo   = (const float*)d_in[3];
    const float* bo   = (const float*)d_in[4];
    const int*   cu   = (const int*)d_in[5];

    const int Dm = 1024;
    int T  = in_sizes[0] / Dm;
    int Bn = in_sizes[5] - 1;
    int Spad = ((T + 63) / 64) * 64;

    auto al = [](size_t v) { return (v + 255) & ~(size_t)255; };
    char* w = (char*)d_ws;
    size_t off = 0;
    f16* xh     = (f16*)(w + off); off = al(off + (size_t)2 * T * 1024);
    f16* qkvh   = (f16*)(w + off); off = al(off + (size_t)2 * T * 3072);
    f16* wqkvT  = (f16*)(w + off); off = al(off + (size_t)2 * 3072 * 1024);
    f16* woT    = (f16*)(w + off); off = al(off + (size_t)2 * 1024 * 1024);
    f16* qhp    = (f16*)(w + off); off = al(off + (size_t)2 * T * 1024);
    f16* khp    = (f16*)(w + off); off = al(off + (size_t)2 * T * 1024);
    f16* vtp    = (f16*)(w + off); off = al(off + (size_t)2 * Bn * 16 * 64 * (size_t)Spad);
    f16* ohp    = (f16*)(w + off); off = al(off + (size_t)2 * T * 1024);
    (void)ws_size;

    // 1. x -> fp16
    {
        int n = T * 1024;
        cvt_x<<<(n / 4 + 255) / 256, 256, 0, stream>>>(x, xh, n);
    }
    // 2. transpose weights
    wtrans<<<dim3(3072 / 64, 1024 / 64), 256, 0, stream>>>(Wqkv, wqkvT, 1024, 3072);
    wtrans<<<dim3(1024 / 64, 1024 / 64), 256, 0, stream>>>(Wo, woT, 1024, 1024);
    // 3. QKV GEMM (+bias) -> fp16
    {
        dim3 g(3072 / 64, (T + 63) / 64);
        gemm_f16<<<g, 256, 0, stream>>>(xh, wqkvT, bqkv, qkvh, nullptr, T, 3072, 1024);
    }
    // 4. RoPE
    {
        int total = T * 512;
        rope_qk<<<(total + 255) / 256, 256, 0, stream>>>(qkvh, cu, Bn, T, qhp, khp);
    }
    // 5. V transpose
    v_trans<<<dim3((T + 63) / 64, 16), 256, 0, stream>>>(qkvh, cu, Bn, T, Spad, vtp);
    // 6. attention
    attn_fwd<<<dim3((T + 15) / 16, 16, Bn), 64, 0, stream>>>(qhp, khp, vtp, cu, ohp, Spad);
    // 7. output GEMM (+bias) -> fp32 d_out
    {
        dim3 g(1024 / 64, (T + 63) / 64);
        gemm_f16<<<g, 256, 0, stream>>>(ohp, woT, bo, nullptr, (float*)d_out, T, 1024, 1024);
    }
}

// Round 3
// 195.188 us; speedup vs baseline: 2.0237x; 2.0237x over previous
//
#include <hip/hip_runtime.h>

typedef _Float16 f16;
typedef _Float16 f16x8 __attribute__((ext_vector_type(8)));
typedef _Float16 f16x4 __attribute__((ext_vector_type(4)));
typedef float f32x4 __attribute__((ext_vector_type(4)));

#define MFMA16(a, b, c) __builtin_amdgcn_mfma_f32_16x16x32_f16((a), (b), (c), 0, 0, 0)

typedef __attribute__((address_space(3))) void lds_void;
typedef const __attribute__((address_space(1))) void g_void;
__device__ __forceinline__ void async_copy16(void* lds, const void* g) {
    __builtin_amdgcn_global_load_lds((g_void*)g, (lds_void*)lds, 16, 0, 0);
}

// ---------------------------------------------------------------------------
// fp32 -> fp16 conversion (x)
__global__ void cvt_x(const float* __restrict__ in, f16* __restrict__ out, int n) {
    int i4 = (blockIdx.x * 256 + threadIdx.x) * 4;
    if (i4 >= n) return;
    float4 v = *reinterpret_cast<const float4*>(in + i4);
    f16x4 o;
    o[0] = (f16)v.x; o[1] = (f16)v.y; o[2] = (f16)v.z; o[3] = (f16)v.w;
    *reinterpret_cast<f16x4*>(out + i4) = o;
}

// ---------------------------------------------------------------------------
// transpose fp32 [K][N] -> fp16 [N][K]   (K,N multiples of 64)
__global__ void wtrans(const float* __restrict__ in, f16* __restrict__ out, int K, int N) {
    __shared__ f16 tile[64][65];
    int n0 = blockIdx.x * 64, k0 = blockIdx.y * 64;
    int c = threadIdx.x & 63, rb = threadIdx.x >> 6;
#pragma unroll
    for (int it = 0; it < 16; ++it) {
        int r = rb + it * 4;
        tile[r][c] = (f16)in[(size_t)(k0 + r) * N + n0 + c];
    }
    __syncthreads();
#pragma unroll
    for (int it = 0; it < 16; ++it) {
        int rr = rb + it * 4;
        out[(size_t)(n0 + rr) * K + k0 + c] = tile[c][rr];
    }
}

// ---------------------------------------------------------------------------
// m97-structure GEMM: C[M][N] = A[M][K] @ Bt[N][K]^T + bias.
// 128x128 tile, BK=32, 4 waves, double-buffered LDS via global_load_lds(16B).
#define BM 128
#define BN 128
#define BKK 32
__global__ __launch_bounds__(256) void gemm_tile(
    const f16* __restrict__ A, const f16* __restrict__ Bt,
    const float* __restrict__ bias, f16* __restrict__ Ch, float* __restrict__ Cf,
    int M, int N, int K) {
    __shared__ f16 lA[2][BM * BKK];  // 8 KB per buffer
    __shared__ f16 lB[2][BN * BKK];
    int tid = threadIdx.x;
    int lane = tid & 63, w = tid >> 6;
    int lr = lane & 15, lg = lane >> 4;
    int wm = (w & 1) * 64, wn = (w >> 1) * 64;
    int bx = blockIdx.x, by = blockIdx.y;

    // staging: issue i covers rows i*64 + tid/4, col chunk (tid&3)*8 (16B/lane)
    int srow = tid >> 2;
    int scol = (tid & 3) * 8;
    const f16* ga0 = A  + (size_t)min(by * BM + srow,      M - 1) * K + scol;
    const f16* ga1 = A  + (size_t)min(by * BM + 64 + srow, M - 1) * K + scol;
    const f16* gb0 = Bt + (size_t)min(bx * BN + srow,      N - 1) * K + scol;
    const f16* gb1 = Bt + (size_t)min(bx * BN + 64 + srow, N - 1) * K + scol;

    f32x4 acc[4][4] = {};
    int NT = K / BKK;

#define STAGE(curb, kt) do {                                        \
        int ko = (kt) * BKK;                                        \
        async_copy16(&lA[curb][w * 512],        ga0 + ko);          \
        async_copy16(&lA[curb][2048 + w * 512], ga1 + ko);          \
        async_copy16(&lB[curb][w * 512],        gb0 + ko);          \
        async_copy16(&lB[curb][2048 + w * 512], gb1 + ko);          \
    } while (0)

    STAGE(0, 0);
    __syncthreads();
    int cur = 0;
    for (int kt = 0; kt < NT; ++kt) {
        if (kt + 1 < NT) STAGE(cur ^ 1, kt + 1);
        f16x8 af[4], bf[4];
#pragma unroll
        for (int i = 0; i < 4; ++i) {
            af[i] = *reinterpret_cast<const f16x8*>(&lA[cur][(wm + i * 16 + lr) * BKK + lg * 8]);
            bf[i] = *reinterpret_cast<const f16x8*>(&lB[cur][(wn + i * 16 + lr) * BKK + lg * 8]);
        }
#pragma unroll
        for (int mi = 0; mi < 4; ++mi)
#pragma unroll
            for (int ni = 0; ni < 4; ++ni)
                acc[mi][ni] = MFMA16(af[mi], bf[ni], acc[mi][ni]);
        __syncthreads();
        cur ^= 1;
    }
#undef STAGE

    // epilogue: C[row][col], row = by*128+wm+mi*16+4*lg+r, col = bx*128+wn+ni*16+lr
#pragma unroll
    for (int mi = 0; mi < 4; ++mi) {
#pragma unroll
        for (int ni = 0; ni < 4; ++ni) {
            int col = bx * BN + wn + ni * 16 + lr;
            float bv = bias ? bias[col] : 0.f;
#pragma unroll
            for (int r = 0; r < 4; ++r) {
                int row = by * BM + wm + mi * 16 + 4 * lg + r;
                if (row >= M) continue;
                float v = acc[mi][ni][r] + bv;
                if (Ch) Ch[(size_t)row * N + col] = (f16)v;
                else    Cf[(size_t)row * N + col] = v;
            }
        }
    }
}

// ---------------------------------------------------------------------------
// RoPE on q,k halves of qkv.  qkv layout [T][3*H*DH] fp16 (bias already added).
__global__ void rope_qk(const f16* __restrict__ qkv, const int* __restrict__ cu,
                        int Bn, int T, f16* __restrict__ qh, f16* __restrict__ kh) {
    int idx = blockIdx.x * 256 + threadIdx.x;
    if (idx >= T * 512) return;
    int i = idx & 31;            // rotary pair index 0..31
    int hh = (idx >> 5) & 15;    // head
    int t = idx >> 9;            // token
    int pos = t;
    for (int q = 0; q < Bn; ++q) {
        int lo = cu[q], hi = cu[q + 1];
        if (t >= lo && t < hi) { pos = t - lo; break; }
    }
    float inv = powf(10000.f, -(float)(2 * i) * (1.f / 64.f));
    float ang = (float)pos * inv;
    float sn, cs;
    sincosf(ang, &sn, &cs);
    size_t base = (size_t)t * 3072 + hh * 64 + i;
    float q1 = (float)qkv[base],        q2 = (float)qkv[base + 32];
    float k1 = (float)qkv[base + 1024], k2 = (float)qkv[base + 1056];
    size_t ob = (size_t)t * 1024 + hh * 64 + i;
    qh[ob]      = (f16)(q1 * cs - q2 * sn);
    qh[ob + 32] = (f16)(q2 * cs + q1 * sn);
    kh[ob]      = (f16)(k1 * cs - k2 * sn);
    kh[ob + 32] = (f16)(k2 * cs + k1 * sn);
}

// ---------------------------------------------------------------------------
// Scatter V into per-(b,h) transposed layout vt[b][h][d][pos], pos-contiguous.
__global__ void v_trans(const f16* __restrict__ qkv, const int* __restrict__ cu,
                        int Bn, int T, int Spad, f16* __restrict__ vt) {
    __shared__ f16 tile[64][65];
    int h = blockIdx.y;
    int t0 = blockIdx.x * 64;
    int c = threadIdx.x & 63, rb = threadIdx.x >> 6;
#pragma unroll
    for (int it = 0; it < 16; ++it) {
        int r = rb + it * 4;
        int t = t0 + r;
        f16 v = (f16)0.f;
        if (t < T) v = qkv[(size_t)t * 3072 + 2048 + h * 64 + c];
        tile[r][c] = v;   // tile[token][dim]
    }
    __syncthreads();
    int t = t0 + c;       // this lane's token
    int bb = 0, pos = -1;
    if (t < T) {
        for (int q = 0; q < Bn; ++q) {
            int lo = cu[q], hi = cu[q + 1];
            if (t >= lo && t < hi) { bb = q; pos = t - lo; }
        }
    }
#pragma unroll
    for (int it = 0; it < 16; ++it) {
        int d = rb + it * 4;  // dim
        if (pos >= 0) vt[((size_t)(bb * 16 + h) * 64 + d) * Spad + pos] = tile[c][d];
    }
}

// ---------------------------------------------------------------------------
// Flash attention: one wave per (b, h, 16-q-row block). KV blocks of 32.
__global__ __launch_bounds__(64) void attn_fwd(
    const f16* __restrict__ qh, const f16* __restrict__ kh,
    const f16* __restrict__ vt, const int* __restrict__ cu,
    f16* __restrict__ oh, int Spad) {
    int b = blockIdx.z, h = blockIdx.y;
    int s0 = cu[b];
    int len = cu[b + 1] - s0;
    int q0 = blockIdx.x * 16;
    if (q0 >= len) return;
    int lane = threadIdx.x, lr = lane & 15, lg = lane >> 4;
    __shared__ f16 pl[16 * 32];

    f16x8 qf0 = {}, qf1 = {};
    int qrow = q0 + lr;
    if (qrow < len) {
        const f16* qp = qh + (size_t)(s0 + qrow) * 1024 + h * 64 + 8 * lg;
        qf0 = *reinterpret_cast<const f16x8*>(qp);
        qf1 = *reinterpret_cast<const f16x8*>(qp + 32);
    }

    float mrun[4], lrun[4];
    f32x4 oacc[4];
#pragma unroll
    for (int r = 0; r < 4; ++r) { mrun[r] = -1e30f; lrun[r] = 0.f; }
#pragma unroll
    for (int dt = 0; dt < 4; ++dt) oacc[dt] = (f32x4){0, 0, 0, 0};

    int kend = min(q0 + 16, len);
    for (int kk0 = 0; kk0 < kend; kk0 += 32) {
        f32x4 sa[2];
#pragma unroll
        for (int j = 0; j < 2; ++j) {
            int krow = kk0 + 16 * j + lr;
            f16x8 kf0 = {}, kf1 = {};
            if (krow < len) {
                const f16* kp = kh + (size_t)(s0 + krow) * 1024 + h * 64 + 8 * lg;
                kf0 = *reinterpret_cast<const f16x8*>(kp);
                kf1 = *reinterpret_cast<const f16x8*>(kp + 32);
            }
            f32x4 z = {0, 0, 0, 0};
            z = MFMA16(qf0, kf0, z);
            z = MFMA16(qf1, kf1, z);
            sa[j] = z;
        }
        float pv[2][4], alpha[4];
#pragma unroll
        for (int r = 0; r < 4; ++r) {
            int qr = q0 + 4 * lg + r;
            float sv[2];
            float mx = -1e30f;
#pragma unroll
            for (int j = 0; j < 2; ++j) {
                int kc = kk0 + 16 * j + lr;
                float v = sa[j][r] * 0.125f;
                if (kc > qr || kc >= len) v = -1e30f;
                sv[j] = v;
                mx = fmaxf(mx, v);
            }
            for (int msk = 1; msk < 16; msk <<= 1) mx = fmaxf(mx, __shfl_xor(mx, msk, 64));
            float mnew = fmaxf(mrun[r], mx);
            float al = __expf(mrun[r] - mnew);
            mrun[r] = mnew;
            float rs = 0.f;
#pragma unroll
            for (int j = 0; j < 2; ++j) {
                float p = __expf(sv[j] - mnew);
                pv[j][r] = p;
                rs += p;
            }
            for (int msk = 1; msk < 16; msk <<= 1) rs += __shfl_xor(rs, msk, 64);
            lrun[r] = lrun[r] * al + rs;
            alpha[r] = al;
        }
#pragma unroll
        for (int dt = 0; dt < 4; ++dt)
#pragma unroll
            for (int r = 0; r < 4; ++r) oacc[dt][r] *= alpha[r];
#pragma unroll
        for (int j = 0; j < 2; ++j)
#pragma unroll
            for (int r = 0; r < 4; ++r)
                pl[(4 * lg + r) * 32 + 16 * j + lr] = (f16)pv[j][r];
        __syncthreads();
        f16x8 pa = *reinterpret_cast<const f16x8*>(pl + lr * 32 + 8 * lg);
        const f16* vb = vt + ((size_t)(b * 16 + h) * 64) * Spad;
#pragma unroll
        for (int dt = 0; dt < 4; ++dt) {
            f16x8 vf = *reinterpret_cast<const f16x8*>(vb + (size_t)(16 * dt + lr) * Spad + kk0 + 8 * lg);
            oacc[dt] = MFMA16(pa, vf, oacc[dt]);
        }
        __syncthreads();
    }
#pragma unroll
    for (int dt = 0; dt < 4; ++dt)
#pragma unroll
        for (int r = 0; r < 4; ++r) {
            int qr = q0 + 4 * lg + r;
            if (qr < len)
                oh[(size_t)(s0 + qr) * 1024 + h * 64 + 16 * dt + lr] = (f16)(oacc[dt][r] / lrun[r]);
        }
}

// ---------------------------------------------------------------------------
extern "C" void kernel_launch(void* const* d_in, const int* in_sizes, int n_in,
                              void* d_out, int out_size, void* d_ws, size_t ws_size,
                              hipStream_t stream) {
    const float* x    = (const float*)d_in[0];
    const float* Wqkv = (const float*)d_in[1];
    const float* bqkv = (const float*)d_in[2];
    const float* Wo   = (const float*)d_in[3];
    const float* bo   = (const float*)d_in[4];
    const int*   cu   = (const int*)d_in[5];

    const int Dm = 1024;
    int T  = in_sizes[0] / Dm;
    int Bn = in_sizes[5] - 1;
    int Spad = ((T + 63) / 64) * 64;

    auto al = [](size_t v) { return (v + 255) & ~(size_t)255; };
    char* w = (char*)d_ws;
    size_t off = 0;
    f16* xh     = (f16*)(w + off); off = al(off + (size_t)2 * T * 1024);
    f16* qkvh   = (f16*)(w + off); off = al(off + (size_t)2 * T * 3072);
    f16* wqkvT  = (f16*)(w + off); off = al(off + (size_t)2 * 3072 * 1024);
    f16* woT    = (f16*)(w + off); off = al(off + (size_t)2 * 1024 * 1024);
    f16* qhp    = (f16*)(w + off); off = al(off + (size_t)2 * T * 1024);
    f16* khp    = (f16*)(w + off); off = al(off + (size_t)2 * T * 1024);
    f16* vtp    = (f16*)(w + off); off = al(off + (size_t)2 * Bn * 16 * 64 * (size_t)Spad);
    f16* ohp    = (f16*)(w + off); off = al(off + (size_t)2 * T * 1024);
    (void)ws_size;

    // 1. x -> fp16
    {
        int n = T * 1024;
        cvt_x<<<(n / 4 + 255) / 256, 256, 0, stream>>>(x, xh, n);
    }
    // 2. transpose weights
    wtrans<<<dim3(3072 / 64, 1024 / 64), 256, 0, stream>>>(Wqkv, wqkvT, 1024, 3072);
    wtrans<<<dim3(1024 / 64, 1024 / 64), 256, 0, stream>>>(Wo, woT, 1024, 1024);
    // 3. QKV GEMM (+bias) -> fp16
    {
        dim3 g(3072 / BN, (T + BM - 1) / BM);
        gemm_tile<<<g, 256, 0, stream>>>(xh, wqkvT, bqkv, qkvh, nullptr, T, 3072, 1024);
    }
    // 4. RoPE
    {
        int total = T * 512;
        rope_qk<<<(total + 255) / 256, 256, 0, stream>>>(qkvh, cu, Bn, T, qhp, khp);
    }
    // 5. V transpose
    v_trans<<<dim3((T + 63) / 64, 16), 256, 0, stream>>>(qkvh, cu, Bn, T, Spad, vtp);
    // 6. attention
    attn_fwd<<<dim3((T + 15) / 16, 16, Bn), 64, 0, stream>>>(qhp, khp, vtp, cu, ohp, Spad);
    // 7. output GEMM (+bias) -> fp32 d_out
    {
        dim3 g(1024 / BN, (T + BM - 1) / BM);
        gemm_tile<<<g, 256, 0, stream>>>(ohp, woT, bo, nullptr, (float*)d_out, T, 1024, 1024);
    }
}

// Round 4
// 156.450 us; speedup vs baseline: 2.5247x; 1.2476x over previous
//
#include <hip/hip_runtime.h>

typedef _Float16 f16;
typedef _Float16 f16x8 __attribute__((ext_vector_type(8)));
typedef _Float16 f16x4 __attribute__((ext_vector_type(4)));
typedef float f32x4 __attribute__((ext_vector_type(4)));

#define MFMA16(a, b, c) __builtin_amdgcn_mfma_f32_16x16x32_f16((a), (b), (c), 0, 0, 0)

typedef __attribute__((address_space(3))) void lds_void;
typedef const __attribute__((address_space(1))) void g_void;
__device__ __forceinline__ void async_copy16(void* lds, const void* g) {
    __builtin_amdgcn_global_load_lds((g_void*)g, (lds_void*)lds, 16, 0, 0);
}

// ---------------------------------------------------------------------------
// fp32 -> fp16 conversion (x)
__global__ void cvt_x(const float* __restrict__ in, f16* __restrict__ out, int n) {
    int i4 = (blockIdx.x * 256 + threadIdx.x) * 4;
    if (i4 >= n) return;
    float4 v = *reinterpret_cast<const float4*>(in + i4);
    f16x4 o;
    o[0] = (f16)v.x; o[1] = (f16)v.y; o[2] = (f16)v.z; o[3] = (f16)v.w;
    *reinterpret_cast<f16x4*>(out + i4) = o;
}

// ---------------------------------------------------------------------------
// transpose fp32 [K][N] -> fp16 [N][K]   (K,N multiples of 64)
__global__ void wtrans(const float* __restrict__ in, f16* __restrict__ out, int K, int N) {
    __shared__ f16 tile[64][65];
    int n0 = blockIdx.x * 64, k0 = blockIdx.y * 64;
    int c = threadIdx.x & 63, rb = threadIdx.x >> 6;
#pragma unroll
    for (int it = 0; it < 16; ++it) {
        int r = rb + it * 4;
        tile[r][c] = (f16)in[(size_t)(k0 + r) * N + n0 + c];
    }
    __syncthreads();
#pragma unroll
    for (int it = 0; it < 16; ++it) {
        int rr = rb + it * 4;
        out[(size_t)(n0 + rr) * K + k0 + c] = tile[c][rr];
    }
}

// ---------------------------------------------------------------------------
// m97-structure GEMM: C[M][N] = A[M][K] @ Bt[N][K]^T + bias.
#define BM 128
#define BN 128
#define BKK 32
__global__ __launch_bounds__(256) void gemm_tile(
    const f16* __restrict__ A, const f16* __restrict__ Bt,
    const float* __restrict__ bias, f16* __restrict__ Ch, float* __restrict__ Cf,
    int M, int N, int K) {
    __shared__ f16 lA[2][BM * BKK];
    __shared__ f16 lB[2][BN * BKK];
    int tid = threadIdx.x;
    int lane = tid & 63, w = tid >> 6;
    int lr = lane & 15, lg = lane >> 4;
    int wm = (w & 1) * 64, wn = (w >> 1) * 64;
    int bx = blockIdx.x, by = blockIdx.y;

    int srow = tid >> 2;
    int scol = (tid & 3) * 8;
    const f16* ga0 = A  + (size_t)min(by * BM + srow,      M - 1) * K + scol;
    const f16* ga1 = A  + (size_t)min(by * BM + 64 + srow, M - 1) * K + scol;
    const f16* gb0 = Bt + (size_t)min(bx * BN + srow,      N - 1) * K + scol;
    const f16* gb1 = Bt + (size_t)min(bx * BN + 64 + srow, N - 1) * K + scol;

    f32x4 acc[4][4] = {};
    int NT = K / BKK;

#define STAGE(curb, kt) do {                                        \
        int ko = (kt) * BKK;                                        \
        async_copy16(&lA[curb][w * 512],        ga0 + ko);          \
        async_copy16(&lA[curb][2048 + w * 512], ga1 + ko);          \
        async_copy16(&lB[curb][w * 512],        gb0 + ko);          \
        async_copy16(&lB[curb][2048 + w * 512], gb1 + ko);          \
    } while (0)

    STAGE(0, 0);
    __syncthreads();
    int cur = 0;
    for (int kt = 0; kt < NT; ++kt) {
        if (kt + 1 < NT) STAGE(cur ^ 1, kt + 1);
        f16x8 af[4], bf[4];
#pragma unroll
        for (int i = 0; i < 4; ++i) {
            af[i] = *reinterpret_cast<const f16x8*>(&lA[cur][(wm + i * 16 + lr) * BKK + lg * 8]);
            bf[i] = *reinterpret_cast<const f16x8*>(&lB[cur][(wn + i * 16 + lr) * BKK + lg * 8]);
        }
#pragma unroll
        for (int mi = 0; mi < 4; ++mi)
#pragma unroll
            for (int ni = 0; ni < 4; ++ni)
                acc[mi][ni] = MFMA16(af[mi], bf[ni], acc[mi][ni]);
        __syncthreads();
        cur ^= 1;
    }
#undef STAGE

#pragma unroll
    for (int mi = 0; mi < 4; ++mi) {
#pragma unroll
        for (int ni = 0; ni < 4; ++ni) {
            int col = bx * BN + wn + ni * 16 + lr;
            float bv = bias ? bias[col] : 0.f;
#pragma unroll
            for (int r = 0; r < 4; ++r) {
                int row = by * BM + wm + mi * 16 + 4 * lg + r;
                if (row >= M) continue;
                float v = acc[mi][ni][r] + bv;
                if (Ch) Ch[(size_t)row * N + col] = (f16)v;
                else    Cf[(size_t)row * N + col] = v;
            }
        }
    }
}

// ---------------------------------------------------------------------------
// RoPE on q,k halves of qkv -> head-major padded layout [(b*16+h)*Spad+pos][64].
__global__ void rope_qk(const f16* __restrict__ qkv, const int* __restrict__ cu,
                        int Bn, int T, int Spad,
                        f16* __restrict__ qh2, f16* __restrict__ kh2) {
    int idx = blockIdx.x * 256 + threadIdx.x;
    if (idx >= T * 512) return;
    int i = idx & 31;            // rotary pair index 0..31
    int hh = (idx >> 5) & 15;    // head
    int t = idx >> 9;            // token
    int b = 0, pos = t;
    for (int q = 0; q < Bn; ++q) {
        int lo = cu[q], hi = cu[q + 1];
        if (t >= lo && t < hi) { b = q; pos = t - lo; break; }
    }
    // 10000^(-2i/64) = 2^(-i * log2(10000)/32)
    float inv = exp2f((float)i * (-13.287712379549449f / 32.f));
    float ang = (float)pos * inv;
    float sn, cs;
    __sincosf(ang, &sn, &cs);
    size_t base = (size_t)t * 3072 + hh * 64 + i;
    float q1 = (float)qkv[base],        q2 = (float)qkv[base + 32];
    float k1 = (float)qkv[base + 1024], k2 = (float)qkv[base + 1056];
    size_t ob = ((size_t)(b * 16 + hh) * Spad + pos) * 64 + i;
    qh2[ob]      = (f16)(q1 * cs - q2 * sn);
    qh2[ob + 32] = (f16)(q2 * cs + q1 * sn);
    kh2[ob]      = (f16)(k1 * cs - k2 * sn);
    kh2[ob + 32] = (f16)(k2 * cs + k1 * sn);
}

// ---------------------------------------------------------------------------
// Scatter V into per-(b,h) transposed layout vt[b][h][d][pos], pos-contiguous.
__global__ void v_trans(const f16* __restrict__ qkv, const int* __restrict__ cu,
                        int Bn, int T, int Spad, f16* __restrict__ vt) {
    __shared__ f16 tile[64][65];
    int h = blockIdx.y;
    int t0 = blockIdx.x * 64;
    int c = threadIdx.x & 63, rb = threadIdx.x >> 6;
#pragma unroll
    for (int it = 0; it < 16; ++it) {
        int r = rb + it * 4;
        int t = t0 + r;
        f16 v = (f16)0.f;
        if (t < T) v = qkv[(size_t)t * 3072 + 2048 + h * 64 + c];
        tile[r][c] = v;
    }
    __syncthreads();
    int t = t0 + c;
    int bb = 0, pos = -1;
    if (t < T) {
        for (int q = 0; q < Bn; ++q) {
            int lo = cu[q], hi = cu[q + 1];
            if (t >= lo && t < hi) { bb = q; pos = t - lo; }
        }
    }
#pragma unroll
    for (int it = 0; it < 16; ++it) {
        int d = rb + it * 4;
        if (pos >= 0) vt[((size_t)(bb * 16 + h) * 64 + d) * Spad + pos] = tile[c][d];
    }
}

// ---------------------------------------------------------------------------
// Flash attention: one wave per (b, h, 32-q-row block). KV blocks of 32.
// Swapped operands: S^T = mfma(K, Q) -> lane owns q-col; O^T = mfma(V^T, P)
// -> oacc q-in-lane, so softmax stats stay lane-local.
__global__ __launch_bounds__(64) void attn_fwd(
    const f16* __restrict__ qh2, const f16* __restrict__ kh2,
    const f16* __restrict__ vt, const int* __restrict__ cu,
    f16* __restrict__ oh, int Spad) {
    int b = blockIdx.z, h = blockIdx.y;
    int bh = b * 16 + h;
    int s0 = cu[b];
    int len = cu[b + 1] - s0;
    int q0 = blockIdx.x * 32;
    if (q0 >= len) return;
    int lane = threadIdx.x & 63, lr = lane & 15, lg = lane >> 4;
    __shared__ f16 pl[2][16][40];   // [qt][q-row][k(32) padded to 40]

    const f16* qbase = qh2 + (size_t)bh * Spad * 64;
    const f16* kbase = kh2 + (size_t)bh * Spad * 64;
    const f16* vbase = vt  + (size_t)bh * 64 * Spad;

    f16x8 qf[2][2];
#pragma unroll
    for (int qt = 0; qt < 2; ++qt) {
        const f16* qp = qbase + (size_t)(q0 + 16 * qt + lr) * 64 + 8 * lg;
        qf[qt][0] = *reinterpret_cast<const f16x8*>(qp);
        qf[qt][1] = *reinterpret_cast<const f16x8*>(qp + 32);
    }
    float mrun[2] = {-1e30f, -1e30f}, lrun[2] = {0.f, 0.f};
    f32x4 oacc[2][4] = {};   // [qt][dt]: row = d_local = 4*lg+r, col = q = lr

    int kend = min(q0 + 32, len);
    for (int kk0 = 0; kk0 < kend; kk0 += 32) {
        f16x8 kf[2][2];
#pragma unroll
        for (int j = 0; j < 2; ++j) {
            const f16* kp = kbase + (size_t)(kk0 + 16 * j + lr) * 64 + 8 * lg;
            kf[j][0] = *reinterpret_cast<const f16x8*>(kp);
            kf[j][1] = *reinterpret_cast<const f16x8*>(kp + 32);
        }
        // S^T tiles: D[row=k_local=4lg+r][col=q=lr]
        f32x4 st[2][2];
#pragma unroll
        for (int qt = 0; qt < 2; ++qt)
#pragma unroll
            for (int j = 0; j < 2; ++j) {
                f32x4 z = {0, 0, 0, 0};
                z = MFMA16(kf[j][0], qf[qt][0], z);
                z = MFMA16(kf[j][1], qf[qt][1], z);
                st[qt][j] = z;
            }
        // online softmax: q = lr is lane-local; reduce over k via regs + lg butterfly
#pragma unroll
        for (int qt = 0; qt < 2; ++qt) {
            int qr = q0 + 16 * qt + lr;
            float sv[2][4];
            float mx = -1e30f;
#pragma unroll
            for (int j = 0; j < 2; ++j)
#pragma unroll
                for (int r = 0; r < 4; ++r) {
                    int kc = kk0 + 16 * j + 4 * lg + r;
                    float v = st[qt][j][r] * 0.125f;
                    if (kc > qr || kc >= len) v = -1e30f;
                    sv[j][r] = v;
                    mx = fmaxf(mx, v);
                }
            mx = fmaxf(mx, __shfl_xor(mx, 16, 64));
            mx = fmaxf(mx, __shfl_xor(mx, 32, 64));
            float mnew = fmaxf(mrun[qt], mx);
            float al = __expf(mrun[qt] - mnew);
            mrun[qt] = mnew;
            float rs = 0.f;
            f16x4 pk0, pk1;
#pragma unroll
            for (int r = 0; r < 4; ++r) {
                float p0 = __expf(sv[0][r] - mnew);
                float p1 = __expf(sv[1][r] - mnew);
                rs += p0 + p1;
                pk0[r] = (f16)p0;
                pk1[r] = (f16)p1;
            }
            rs += __shfl_xor(rs, 16, 64);
            rs += __shfl_xor(rs, 32, 64);
            lrun[qt] = lrun[qt] * al + rs;
            // P^T -> LDS as P[q][k] (8B vector writes)
            *reinterpret_cast<f16x4*>(&pl[qt][lr][4 * lg])      = pk0;
            *reinterpret_cast<f16x4*>(&pl[qt][lr][16 + 4 * lg]) = pk1;
            // rescale O (lane-local: col q = lr)
#pragma unroll
            for (int dt = 0; dt < 4; ++dt)
#pragma unroll
                for (int r = 0; r < 4; ++r) oacc[qt][dt][r] *= al;
        }
        __syncthreads();
        f16x8 pa0 = *reinterpret_cast<const f16x8*>(&pl[0][lr][8 * lg]);
        f16x8 pa1 = *reinterpret_cast<const f16x8*>(&pl[1][lr][8 * lg]);
#pragma unroll
        for (int dt = 0; dt < 4; ++dt) {
            f16x8 vf = *reinterpret_cast<const f16x8*>(vbase + (size_t)(16 * dt + lr) * Spad + kk0 + 8 * lg);
            oacc[0][dt] = MFMA16(vf, pa0, oacc[0][dt]);
            oacc[1][dt] = MFMA16(vf, pa1, oacc[1][dt]);
        }
        __syncthreads();
    }
    // store: O[q=lr][d=16dt+4lg+r], vectorized 8B per (qt,dt)
#pragma unroll
    for (int qt = 0; qt < 2; ++qt) {
        int qr = q0 + 16 * qt + lr;
        if (qr >= len) continue;
        float linv = 1.f / lrun[qt];
        f16* orow = oh + (size_t)(s0 + qr) * 1024 + h * 64;
#pragma unroll
        for (int dt = 0; dt < 4; ++dt) {
            f16x4 ov;
#pragma unroll
            for (int r = 0; r < 4; ++r) ov[r] = (f16)(oacc[qt][dt][r] * linv);
            *reinterpret_cast<f16x4*>(orow + 16 * dt + 4 * lg) = ov;
        }
    }
}

// ---------------------------------------------------------------------------
extern "C" void kernel_launch(void* const* d_in, const int* in_sizes, int n_in,
                              void* d_out, int out_size, void* d_ws, size_t ws_size,
                              hipStream_t stream) {
    const float* x    = (const float*)d_in[0];
    const float* Wqkv = (const float*)d_in[1];
    const float* bqkv = (const float*)d_in[2];
    const float* Wo   = (const float*)d_in[3];
    const float* bo   = (const float*)d_in[4];
    const int*   cu   = (const int*)d_in[5];

    const int Dm = 1024;
    int T  = in_sizes[0] / Dm;
    int Bn = in_sizes[5] - 1;
    int Spad = 1024;  // max_seqlen (padded); q/k/v per-head buffers use this

    auto al = [](size_t v) { return (v + 255) & ~(size_t)255; };
    char* w = (char*)d_ws;
    size_t off = 0;
    f16* xh     = (f16*)(w + off); off = al(off + (size_t)2 * T * 1024);
    f16* qkvh   = (f16*)(w + off); off = al(off + (size_t)2 * T * 3072);
    f16* wqkvT  = (f16*)(w + off); off = al(off + (size_t)2 * 3072 * 1024);
    f16* woT    = (f16*)(w + off); off = al(off + (size_t)2 * 1024 * 1024);
    f16* qh2    = (f16*)(w + off); off = al(off + (size_t)2 * Bn * 16 * 64 * (size_t)Spad);
    f16* kh2    = (f16*)(w + off); off = al(off + (size_t)2 * Bn * 16 * 64 * (size_t)Spad);
    f16* vtp    = (f16*)(w + off); off = al(off + (size_t)2 * Bn * 16 * 64 * (size_t)Spad);
    f16* ohp    = (f16*)(w + off); off = al(off + (size_t)2 * T * 1024);
    (void)ws_size;

    // 1. x -> fp16
    {
        int n = T * 1024;
        cvt_x<<<(n / 4 + 255) / 256, 256, 0, stream>>>(x, xh, n);
    }
    // 2. transpose weights
    wtrans<<<dim3(3072 / 64, 1024 / 64), 256, 0, stream>>>(Wqkv, wqkvT, 1024, 3072);
    wtrans<<<dim3(1024 / 64, 1024 / 64), 256, 0, stream>>>(Wo, woT, 1024, 1024);
    // 3. QKV GEMM (+bias) -> fp16
    {
        dim3 g(3072 / BN, (T + BM - 1) / BM);
        gemm_tile<<<g, 256, 0, stream>>>(xh, wqkvT, bqkv, qkvh, nullptr, T, 3072, 1024);
    }
    // 4. RoPE -> head-major q/k
    {
        int total = T * 512;
        rope_qk<<<(total + 255) / 256, 256, 0, stream>>>(qkvh, cu, Bn, T, Spad, qh2, kh2);
    }
    // 5. V transpose
    v_trans<<<dim3((T + 63) / 64, 16), 256, 0, stream>>>(qkvh, cu, Bn, T, Spad, vtp);
    // 6. attention
    attn_fwd<<<dim3(Spad / 32, 16, Bn), 64, 0, stream>>>(qh2, kh2, vtp, cu, ohp, Spad);
    // 7. output GEMM (+bias) -> fp32 d_out
    {
        dim3 g(1024 / BN, (T + BM - 1) / BM);
        gemm_tile<<<g, 256, 0, stream>>>(ohp, woT, bo, nullptr, (float*)d_out, T, 1024, 1024);
    }
}

// Round 8
// 148.966 us; speedup vs baseline: 2.6516x; 1.0502x over previous
//
#include <hip/hip_runtime.h>

typedef _Float16 f16;
typedef _Float16 f16x8 __attribute__((ext_vector_type(8)));
typedef _Float16 f16x4 __attribute__((ext_vector_type(4)));
typedef float f32x4 __attribute__((ext_vector_type(4)));

#define MFMA16(a, b, c) __builtin_amdgcn_mfma_f32_16x16x32_f16((a), (b), (c), 0, 0, 0)

typedef __attribute__((address_space(3))) void lds_void;
typedef const __attribute__((address_space(1))) void g_void;
__device__ __forceinline__ void async_copy16(void* lds, const void* g) {
    __builtin_amdgcn_global_load_lds((g_void*)g, (lds_void*)lds, 16, 0, 0);
}

// ---------------------------------------------------------------------------
// fp32 -> fp16 conversion (x)
__global__ void cvt_x(const float* __restrict__ in, f16* __restrict__ out, int n) {
    int i4 = (blockIdx.x * 256 + threadIdx.x) * 4;
    if (i4 >= n) return;
    float4 v = *reinterpret_cast<const float4*>(in + i4);
    f16x4 o;
    o[0] = (f16)v.x; o[1] = (f16)v.y; o[2] = (f16)v.z; o[3] = (f16)v.w;
    *reinterpret_cast<f16x4*>(out + i4) = o;
}

// ---------------------------------------------------------------------------
// transpose fp32 [K][N] -> fp16 [N][K]   (K,N multiples of 64)
__global__ void wtrans(const float* __restrict__ in, f16* __restrict__ out, int K, int N) {
    __shared__ f16 tile[64][65];
    int n0 = blockIdx.x * 64, k0 = blockIdx.y * 64;
    int c = threadIdx.x & 63, rb = threadIdx.x >> 6;
#pragma unroll
    for (int it = 0; it < 16; ++it) {
        int r = rb + it * 4;
        tile[r][c] = (f16)in[(size_t)(k0 + r) * N + n0 + c];
    }
    __syncthreads();
#pragma unroll
    for (int it = 0; it < 16; ++it) {
        int rr = rb + it * 4;
        out[(size_t)(n0 + rr) * K + k0 + c] = tile[c][rr];
    }
}

// ---------------------------------------------------------------------------
// m97-structure GEMM: C[M][N] = A[M][K] @ Bt[N][K]^T + bias.
#define BM 128
#define BN 128
#define BKK 32
__global__ __launch_bounds__(256) void gemm_tile(
    const f16* __restrict__ A, const f16* __restrict__ Bt,
    const float* __restrict__ bias, f16* __restrict__ Ch, float* __restrict__ Cf,
    int M, int N, int K) {
    __shared__ f16 lA[2][BM * BKK];
    __shared__ f16 lB[2][BN * BKK];
    int tid = threadIdx.x;
    int lane = tid & 63, w = tid >> 6;
    int lr = lane & 15, lg = lane >> 4;
    int wm = (w & 1) * 64, wn = (w >> 1) * 64;
    int bx = blockIdx.x, by = blockIdx.y;

    int srow = tid >> 2;
    int scol = (tid & 3) * 8;
    const f16* ga0 = A  + (size_t)min(by * BM + srow,      M - 1) * K + scol;
    const f16* ga1 = A  + (size_t)min(by * BM + 64 + srow, M - 1) * K + scol;
    const f16* gb0 = Bt + (size_t)min(bx * BN + srow,      N - 1) * K + scol;
    const f16* gb1 = Bt + (size_t)min(bx * BN + 64 + srow, N - 1) * K + scol;

    f32x4 acc[4][4] = {};
    int NT = K / BKK;

#define STAGE(curb, kt) do {                                        \
        int ko = (kt) * BKK;                                        \
        async_copy16(&lA[curb][w * 512],        ga0 + ko);          \
        async_copy16(&lA[curb][2048 + w * 512], ga1 + ko);          \
        async_copy16(&lB[curb][w * 512],        gb0 + ko);          \
        async_copy16(&lB[curb][2048 + w * 512], gb1 + ko);          \
    } while (0)

    STAGE(0, 0);
    __syncthreads();
    int cur = 0;
    for (int kt = 0; kt < NT; ++kt) {
        if (kt + 1 < NT) STAGE(cur ^ 1, kt + 1);
        f16x8 af[4], bf[4];
#pragma unroll
        for (int i = 0; i < 4; ++i) {
            af[i] = *reinterpret_cast<const f16x8*>(&lA[cur][(wm + i * 16 + lr) * BKK + lg * 8]);
            bf[i] = *reinterpret_cast<const f16x8*>(&lB[cur][(wn + i * 16 + lr) * BKK + lg * 8]);
        }
#pragma unroll
        for (int mi = 0; mi < 4; ++mi)
#pragma unroll
            for (int ni = 0; ni < 4; ++ni)
                acc[mi][ni] = MFMA16(af[mi], bf[ni], acc[mi][ni]);
        __syncthreads();
        cur ^= 1;
    }
#undef STAGE

#pragma unroll
    for (int mi = 0; mi < 4; ++mi) {
#pragma unroll
        for (int ni = 0; ni < 4; ++ni) {
            int col = bx * BN + wn + ni * 16 + lr;
            float bv = bias ? bias[col] : 0.f;
#pragma unroll
            for (int r = 0; r < 4; ++r) {
                int row = by * BM + wm + mi * 16 + 4 * lg + r;
                if (row >= M) continue;
                float v = acc[mi][ni][r] + bv;
                if (Ch) Ch[(size_t)row * N + col] = (f16)v;
                else    Cf[(size_t)row * N + col] = v;
            }
        }
    }
}

// ---------------------------------------------------------------------------
// RoPE on q,k halves of qkv -> head-major padded layout [(b*16+h)*Spad+pos][64].
__global__ void rope_qk(const f16* __restrict__ qkv, const int* __restrict__ cu,
                        int Bn, int T, int Spad,
                        f16* __restrict__ qh2, f16* __restrict__ kh2) {
    int idx = blockIdx.x * 256 + threadIdx.x;
    if (idx >= T * 512) return;
    int i = idx & 31;
    int hh = (idx >> 5) & 15;
    int t = idx >> 9;
    int b = 0, pos = t;
    for (int q = 0; q < Bn; ++q) {
        int lo = cu[q], hi = cu[q + 1];
        if (t >= lo && t < hi) { b = q; pos = t - lo; break; }
    }
    float inv = exp2f((float)i * (-13.287712379549449f / 32.f));
    float ang = (float)pos * inv;
    float sn, cs;
    __sincosf(ang, &sn, &cs);
    size_t base = (size_t)t * 3072 + hh * 64 + i;
    float q1 = (float)qkv[base],        q2 = (float)qkv[base + 32];
    float k1 = (float)qkv[base + 1024], k2 = (float)qkv[base + 1056];
    size_t ob = ((size_t)(b * 16 + hh) * Spad + pos) * 64 + i;
    qh2[ob]      = (f16)(q1 * cs - q2 * sn);
    qh2[ob + 32] = (f16)(q2 * cs + q1 * sn);
    kh2[ob]      = (f16)(k1 * cs - k2 * sn);
    kh2[ob + 32] = (f16)(k2 * cs + k1 * sn);
}

// ---------------------------------------------------------------------------
// Scatter V into per-(b,h) transposed layout vt[b][h][d][pos], pos-contiguous.
__global__ void v_trans(const f16* __restrict__ qkv, const int* __restrict__ cu,
                        int Bn, int T, int Spad, f16* __restrict__ vt) {
    __shared__ f16 tile[64][65];
    int h = blockIdx.y;
    int t0 = blockIdx.x * 64;
    int c = threadIdx.x & 63, rb = threadIdx.x >> 6;
#pragma unroll
    for (int it = 0; it < 16; ++it) {
        int r = rb + it * 4;
        int t = t0 + r;
        f16 v = (f16)0.f;
        if (t < T) v = qkv[(size_t)t * 3072 + 2048 + h * 64 + c];
        tile[r][c] = v;
    }
    __syncthreads();
    int t = t0 + c;
    int bb = 0, pos = -1;
    if (t < T) {
        for (int q = 0; q < Bn; ++q) {
            int lo = cu[q], hi = cu[q + 1];
            if (t >= lo && t < hi) { bb = q; pos = t - lo; }
        }
    }
#pragma unroll
    for (int it = 0; it < 16; ++it) {
        int d = rb + it * 4;
        if (pos >= 0) vt[((size_t)(bb * 16 + h) * 64 + d) * Spad + pos] = tile[c][d];
    }
}

// ---------------------------------------------------------------------------
// Flash attention: round-3-verified kernel VERBATIM (1 wave, 32 q-rows,
// KVBLK=32, swapped-operand MFMA, lane-local softmax, P LDS round-trip with
// barriers). ONLY change: 1D grid + bijective XCD-affinity remap so all
// q-blocks of one (b,h) share wgid&7 (same XCD -> K/V pinned in one L2),
// longest q-blocks dispatched first.
__global__ __launch_bounds__(64) void attn_fwd(
    const f16* __restrict__ qh2, const f16* __restrict__ kh2,
    const f16* __restrict__ vt, const int* __restrict__ cu,
    f16* __restrict__ oh, int Spad, int nq, int Bn) {
    int wgid = blockIdx.x;
    int nbh = Bn * 16;
    int b, h, qi;
    if ((nbh & 7) == 0) {
        int xcd = wgid & 7, rest = wgid >> 3, nbh8 = nbh >> 3;
        int bhhi = rest % nbh8;
        qi = (nq - 1) - rest / nbh8;          // longest blocks first
        int bhv = (bhhi << 3) | xcd;
        b = bhv >> 4; h = bhv & 15;
    } else {
        qi = wgid % nq;
        int bhv = wgid / nq;
        b = bhv >> 4; h = bhv & 15;
    }
    int bh = b * 16 + h;
    int s0 = cu[b];
    int len = cu[b + 1] - s0;
    int q0 = qi * 32;
    if (q0 >= len) return;
    int lane = threadIdx.x & 63, lr = lane & 15, lg = lane >> 4;
    __shared__ f16 pl[2][16][40];   // [qt][q-row][k(32) padded to 40]

    const f16* qbase = qh2 + (size_t)bh * Spad * 64;
    const f16* kbase = kh2 + (size_t)bh * Spad * 64;
    const f16* vbase = vt  + (size_t)bh * 64 * Spad;

    f16x8 qf[2][2];
#pragma unroll
    for (int qt = 0; qt < 2; ++qt) {
        const f16* qp = qbase + (size_t)(q0 + 16 * qt + lr) * 64 + 8 * lg;
        qf[qt][0] = *reinterpret_cast<const f16x8*>(qp);
        qf[qt][1] = *reinterpret_cast<const f16x8*>(qp + 32);
    }
    float mrun[2] = {-1e30f, -1e30f}, lrun[2] = {0.f, 0.f};
    f32x4 oacc[2][4] = {};   // [qt][dt]: row = d_local = 4*lg+r, col = q = lr

    int kend = min(q0 + 32, len);
    for (int kk0 = 0; kk0 < kend; kk0 += 32) {
        f16x8 kf[2][2];
#pragma unroll
        for (int j = 0; j < 2; ++j) {
            const f16* kp = kbase + (size_t)(kk0 + 16 * j + lr) * 64 + 8 * lg;
            kf[j][0] = *reinterpret_cast<const f16x8*>(kp);
            kf[j][1] = *reinterpret_cast<const f16x8*>(kp + 32);
        }
        // S^T tiles: D[row=k_local=4lg+r][col=q=lr]
        f32x4 st[2][2];
#pragma unroll
        for (int qt = 0; qt < 2; ++qt)
#pragma unroll
            for (int j = 0; j < 2; ++j) {
                f32x4 z = {0, 0, 0, 0};
                z = MFMA16(kf[j][0], qf[qt][0], z);
                z = MFMA16(kf[j][1], qf[qt][1], z);
                st[qt][j] = z;
            }
        // online softmax: q = lr is lane-local; reduce over k via regs + lg butterfly
#pragma unroll
        for (int qt = 0; qt < 2; ++qt) {
            int qr = q0 + 16 * qt + lr;
            float sv[2][4];
            float mx = -1e30f;
#pragma unroll
            for (int j = 0; j < 2; ++j)
#pragma unroll
                for (int r = 0; r < 4; ++r) {
                    int kc = kk0 + 16 * j + 4 * lg + r;
                    float v = st[qt][j][r] * 0.125f;
                    if (kc > qr || kc >= len) v = -1e30f;
                    sv[j][r] = v;
                    mx = fmaxf(mx, v);
                }
            mx = fmaxf(mx, __shfl_xor(mx, 16, 64));
            mx = fmaxf(mx, __shfl_xor(mx, 32, 64));
            float mnew = fmaxf(mrun[qt], mx);
            float al = __expf(mrun[qt] - mnew);
            mrun[qt] = mnew;
            float rs = 0.f;
            f16x4 pk0, pk1;
#pragma unroll
            for (int r = 0; r < 4; ++r) {
                float p0 = __expf(sv[0][r] - mnew);
                float p1 = __expf(sv[1][r] - mnew);
                rs += p0 + p1;
                pk0[r] = (f16)p0;
                pk1[r] = (f16)p1;
            }
            rs += __shfl_xor(rs, 16, 64);
            rs += __shfl_xor(rs, 32, 64);
            lrun[qt] = lrun[qt] * al + rs;
            // P^T -> LDS as P[q][k] (8B vector writes)
            *reinterpret_cast<f16x4*>(&pl[qt][lr][4 * lg])      = pk0;
            *reinterpret_cast<f16x4*>(&pl[qt][lr][16 + 4 * lg]) = pk1;
            // rescale O (lane-local: col q = lr)
#pragma unroll
            for (int dt = 0; dt < 4; ++dt)
#pragma unroll
                for (int r = 0; r < 4; ++r) oacc[qt][dt][r] *= al;
        }
        __syncthreads();
        f16x8 pa0 = *reinterpret_cast<const f16x8*>(&pl[0][lr][8 * lg]);
        f16x8 pa1 = *reinterpret_cast<const f16x8*>(&pl[1][lr][8 * lg]);
#pragma unroll
        for (int dt = 0; dt < 4; ++dt) {
            f16x8 vf = *reinterpret_cast<const f16x8*>(vbase + (size_t)(16 * dt + lr) * Spad + kk0 + 8 * lg);
            oacc[0][dt] = MFMA16(vf, pa0, oacc[0][dt]);
            oacc[1][dt] = MFMA16(vf, pa1, oacc[1][dt]);
        }
        __syncthreads();
    }
    // store: O[q=lr][d=16dt+4lg+r], vectorized 8B per (qt,dt)
#pragma unroll
    for (int qt = 0; qt < 2; ++qt) {
        int qr = q0 + 16 * qt + lr;
        if (qr >= len) continue;
        float linv = 1.f / lrun[qt];
        f16* orow = oh + (size_t)(s0 + qr) * 1024 + h * 64;
#pragma unroll
        for (int dt = 0; dt < 4; ++dt) {
            f16x4 ov;
#pragma unroll
            for (int r = 0; r < 4; ++r) ov[r] = (f16)(oacc[qt][dt][r] * linv);
            *reinterpret_cast<f16x4*>(orow + 16 * dt + 4 * lg) = ov;
        }
    }
}

// ---------------------------------------------------------------------------
extern "C" void kernel_launch(void* const* d_in, const int* in_sizes, int n_in,
                              void* d_out, int out_size, void* d_ws, size_t ws_size,
                              hipStream_t stream) {
    const float* x    = (const float*)d_in[0];
    const float* Wqkv = (const float*)d_in[1];
    const float* bqkv = (const float*)d_in[2];
    const float* Wo   = (const float*)d_in[3];
    const float* bo   = (const float*)d_in[4];
    const int*   cu   = (const int*)d_in[5];

    const int Dm = 1024;
    int T  = in_sizes[0] / Dm;
    int Bn = in_sizes[5] - 1;
    int Spad = 1024;  // max_seqlen

    auto al = [](size_t v) { return (v + 255) & ~(size_t)255; };
    char* w = (char*)d_ws;
    size_t off = 0;
    f16* xh     = (f16*)(w + off); off = al(off + (size_t)2 * T * 1024);
    f16* qkvh   = (f16*)(w + off); off = al(off + (size_t)2 * T * 3072);
    f16* wqkvT  = (f16*)(w + off); off = al(off + (size_t)2 * 3072 * 1024);
    f16* woT    = (f16*)(w + off); off = al(off + (size_t)2 * 1024 * 1024);
    f16* qh2    = (f16*)(w + off); off = al(off + (size_t)2 * Bn * 16 * 64 * (size_t)Spad);
    f16* kh2    = (f16*)(w + off); off = al(off + (size_t)2 * Bn * 16 * 64 * (size_t)Spad);
    f16* vtp    = (f16*)(w + off); off = al(off + (size_t)2 * Bn * 16 * 64 * (size_t)Spad);
    f16* ohp    = (f16*)(w + off); off = al(off + (size_t)2 * T * 1024);
    (void)ws_size;

    {
        int n = T * 1024;
        cvt_x<<<(n / 4 + 255) / 256, 256, 0, stream>>>(x, xh, n);
    }
    wtrans<<<dim3(3072 / 64, 1024 / 64), 256, 0, stream>>>(Wqkv, wqkvT, 1024, 3072);
    wtrans<<<dim3(1024 / 64, 1024 / 64), 256, 0, stream>>>(Wo, woT, 1024, 1024);
    {
        dim3 g(3072 / BN, (T + BM - 1) / BM);
        gemm_tile<<<g, 256, 0, stream>>>(xh, wqkvT, bqkv, qkvh, nullptr, T, 3072, 1024);
    }
    {
        int total = T * 512;
        rope_qk<<<(total + 255) / 256, 256, 0, stream>>>(qkvh, cu, Bn, T, Spad, qh2, kh2);
    }
    v_trans<<<dim3((T + 63) / 64, 16), 256, 0, stream>>>(qkvh, cu, Bn, T, Spad, vtp);
    {
        int nq = Spad / 32;
        int ngrid = nq * 16 * Bn;
        attn_fwd<<<ngrid, 64, 0, stream>>>(qh2, kh2, vtp, cu, ohp, Spad, nq, Bn);
    }
    {
        dim3 g(1024 / BN, (T + BM - 1) / BM);
        gemm_tile<<<g, 256, 0, stream>>>(ohp, woT, bo, nullptr, (float*)d_out, T, 1024, 1024);
    }
}